// Round 1
// baseline (321.776 us; speedup 1.0000x reference)
//
#include <hip/hip_runtime.h>
#include <hip/hip_bf16.h>

// RasterPoints: out[b,t,row,col,p] = 1.0, zeros elsewhere.
// B=8, T=25, NP=10, H=W=200. Output = 80,000,000 f32 = 320 MB.
// Memory-bound on the zero-fill; scatter is 2000 stores (negligible).

#define RP_B 8
#define RP_T 25
#define RP_NP 10
#define RP_H 200
#define RP_W 200

__global__ void rp_zero_kernel(float4* __restrict__ out, long long n4) {
    long long i = (long long)blockIdx.x * blockDim.x + threadIdx.x;
    long long stride = (long long)gridDim.x * blockDim.x;
    float4 z = make_float4(0.f, 0.f, 0.f, 0.f);
    for (; i < n4; i += stride) out[i] = z;
}

__global__ void rp_scatter_kernel(const float* __restrict__ x,
                                  const float* __restrict__ res,
                                  const float* __restrict__ org,
                                  float* __restrict__ out) {
    int idx = blockIdx.x * blockDim.x + threadIdx.x;  // over B*T*NP
    const int total = RP_B * RP_T * RP_NP;
    if (idx >= total) return;
    int p  = idx % RP_NP;
    int bt = idx / RP_NP;  // b*T + t

    // x layout: [B,T,NP*2] -> point p of bt at x[bt*NP*2 + p*2 + {0,1}]
    float xc = x[bt * RP_NP * 2 + p * 2 + 0];  // x coord -> col
    float yc = x[bt * RP_NP * 2 + p * 2 + 1];  // y coord -> row
    float r0 = res[bt * 2 + 0];
    float r1 = res[bt * 2 + 1];
    float o0 = org[bt * 2 + 0];
    float o1 = org[bt * 2 + 1];

    int row = (int)(yc / r0 + o0);  // truncation matches astype(int32) for non-negative
    int col = (int)(xc / r1 + o1);

    long long off = ((((long long)bt) * RP_H + row) * RP_W + col) * RP_NP + p;
    out[off] = 1.0f;
}

extern "C" void kernel_launch(void* const* d_in, const int* in_sizes, int n_in,
                              void* d_out, int out_size, void* d_ws, size_t ws_size,
                              hipStream_t stream) {
    const float* x   = (const float*)d_in[0];
    const float* res = (const float*)d_in[1];
    const float* org = (const float*)d_in[2];
    float* out = (float*)d_out;

    // Zero fill: out_size = 80,000,000 (divisible by 4)
    long long n4 = (long long)out_size / 4;
    int zblocks = 2048;
    rp_zero_kernel<<<zblocks, 256, 0, stream>>>((float4*)out, n4);

    const int total = RP_B * RP_T * RP_NP;  // 2000
    rp_scatter_kernel<<<(total + 255) / 256, 256, 0, stream>>>(x, res, org, out);
}

// Round 4
// 310.091 us; speedup vs baseline: 1.0377x; 1.0377x over previous
//
#include <hip/hip_runtime.h>
#include <hip/hip_bf16.h>

// RasterPoints: out[b,t,row,col,p] = 1.0 at 2000 computed positions, zeros elsewhere.
// B=8, T=25, NP=10, H=W=200. Output = 80,000,000 f32 = 320 MB.
// Zero-fill via hipMemsetAsync (rocclr fillBufferAligned path, measured 6.1 TB/s
// on this chip), then a 2000-thread scatter kernel.

#define RP_B 8
#define RP_T 25
#define RP_NP 10
#define RP_H 200
#define RP_W 200

__global__ void rp_scatter_kernel(const float* __restrict__ x,
                                  const float* __restrict__ res,
                                  const float* __restrict__ org,
                                  float* __restrict__ out) {
    int idx = blockIdx.x * blockDim.x + threadIdx.x;  // over B*T*NP
    const int total = RP_B * RP_T * RP_NP;
    if (idx >= total) return;
    int p  = idx % RP_NP;
    int bt = idx / RP_NP;  // b*T + t

    // x layout: [B,T,NP*2] -> point p of bt at x[bt*NP*2 + p*2 + {0,1}]
    float xc = x[bt * RP_NP * 2 + p * 2 + 0];  // x coord -> col
    float yc = x[bt * RP_NP * 2 + p * 2 + 1];  // y coord -> row
    float r0 = res[bt * 2 + 0];
    float r1 = res[bt * 2 + 1];
    float o0 = org[bt * 2 + 0];
    float o1 = org[bt * 2 + 1];

    int row = (int)(yc / r0 + o0);  // truncation == astype(int32) for non-negative
    int col = (int)(xc / r1 + o1);

    long long off = ((((long long)bt) * RP_H + row) * RP_W + col) * RP_NP + p;
    out[off] = 1.0f;
}

extern "C" void kernel_launch(void* const* d_in, const int* in_sizes, int n_in,
                              void* d_out, int out_size, void* d_ws, size_t ws_size,
                              hipStream_t stream) {
    const float* x   = (const float*)d_in[0];
    const float* res = (const float*)d_in[1];
    const float* org = (const float*)d_in[2];
    float* out = (float*)d_out;

    // Zero fill via the rocclr fast path (graph-capturable async memset).
    hipMemsetAsync(out, 0, (size_t)out_size * sizeof(float), stream);

    const int total = RP_B * RP_T * RP_NP;  // 2000
    rp_scatter_kernel<<<(total + 255) / 256, 256, 0, stream>>>(x, res, org, out);
}